// Round 6
// baseline (527.889 us; speedup 1.0000x reference)
//
#include <hip/hip_runtime.h>
#include <math.h>

#define B_ 16
#define L_ 512
#define D_ 768
#define HOPS_ 3
#define LK 64  // shorts per LDS row = 128B = 8 16B slots

typedef __attribute__((ext_vector_type(8))) short s16x8;
typedef __attribute__((ext_vector_type(4))) short s16x4;
typedef __attribute__((ext_vector_type(4))) float f32x4;

typedef __attribute__((address_space(1))) const unsigned gu32;
typedef __attribute__((address_space(3))) unsigned lu32;

// async global->LDS, 16B/lane. LDS dest: wave-uniform base + lane*16 (linear).
__device__ __forceinline__ void gl16(const void* g, void* l) {
  __builtin_amdgcn_global_load_lds((gu32*)g, (lu32*)l, 16, 0, 0);
}

__device__ __forceinline__ short f2bf(float f) {
  unsigned u = __float_as_uint(f);
  unsigned r = (u + 0x7fffu + ((u >> 16) & 1u)) >> 16;
  return (short)r;
}
__device__ __forceinline__ float bf2f(short s) {
  unsigned u = ((unsigned)(unsigned short)s) << 16;
  return __uint_as_float(u);
}
__device__ __forceinline__ float tanh_fast(float x) {
  float e = __expf(2.f * x);  // inf-safe: +inf -> 1, 0 -> -1
  return 1.f - 2.f / (e + 1.f);
}

// READ-side swizzle: phys slot = slot ^ (row&7). LDS written linearly by
// global_load_lds; inverse permutation applied to the per-lane GLOBAL source
// address (sw term). Verified r3-r5: SQ_LDS_BANK_CONFLICT == 0.
__device__ __forceinline__ s16x8* lds_slot(short (*T)[LK], int row, int slot) {
  return (s16x8*)&T[row][(slot ^ (row & 7)) * 8];
}

// 128x128 tile, 4 waves (2x2 of 64x64), K-step 64
__device__ __forceinline__ void mfma4(short (*As)[LK], short (*Bs)[LK],
                                      f32x4 acc[4][4], int wr, int wc, int lq, int lr) {
#pragma unroll
  for (int ks = 0; ks < 2; ++ks) {
    int sl = ks * 4 + lq;
    s16x8 av[4], bv[4];
#pragma unroll
    for (int m = 0; m < 4; ++m) av[m] = *lds_slot(As, wr * 64 + m * 16 + lr, sl);
#pragma unroll
    for (int n = 0; n < 4; ++n) bv[n] = *lds_slot(Bs, wc * 64 + n * 16 + lr, sl);
#pragma unroll
    for (int m = 0; m < 4; ++m)
#pragma unroll
      for (int n = 0; n < 4; ++n)
        acc[m][n] = __builtin_amdgcn_mfma_f32_16x16x32_bf16(av[m], bv[n], acc[m][n], 0, 0, 0);
  }
}

// 64x128 tile, 4 waves (2x2 of 32x64), K-step 64
__device__ __forceinline__ void mfma2(short (*As)[LK], short (*Bs)[LK],
                                      f32x4 acc[2][4], int wr, int wc, int lq, int lr) {
#pragma unroll
  for (int ks = 0; ks < 2; ++ks) {
    int sl = ks * 4 + lq;
    s16x8 av[2], bv[4];
#pragma unroll
    for (int m = 0; m < 2; ++m) av[m] = *lds_slot(As, wr * 32 + m * 16 + lr, sl);
#pragma unroll
    for (int n = 0; n < 4; ++n) bv[n] = *lds_slot(Bs, wc * 64 + n * 16 + lr, sl);
#pragma unroll
    for (int m = 0; m < 2; ++m)
#pragma unroll
      for (int n = 0; n < 4; ++n)
        acc[m][n] = __builtin_amdgcn_mfma_f32_16x16x32_bf16(av[m], bv[n], acc[m][n], 0, 0, 0);
  }
}

__device__ __forceinline__ int xcd_remap(int bid, int n) {
  return (bid & 7) * (n >> 3) + (bid >> 3);
}

// ---------------------------------------------------------------------------
// sim: S[b][i][j] = sum_k A[i][k]*A[j][k].  SPLIT=1: Xs [L][1536] hi|lo,
// virtual K=2304: A segs {hi,lo,hi}, B segs {hi,hi,lo}. 64x128 tile.
// Double-buffered: prefetch K-step k+1 before computing k; 1 barrier/step.
// ---------------------------------------------------------------------------
template <int SPLIT>
__global__ __launch_bounds__(256) void k_sim_mfma(const short* __restrict__ X,
                                                  float* __restrict__ Sout) {
  int wg = xcd_remap(blockIdx.x, gridDim.x);
  int jb = wg & 3, ib = (wg >> 2) & 7, b = wg >> 5;
  int i0 = ib * 64, j0 = jb * 128;
  const int ld = SPLIT ? 1536 : D_;
  const short* Xb = X + (size_t)b * L_ * ld;
  int t = threadIdx.x, lane = t & 63, wid = t >> 6;
  int wr = wid >> 1, wc = wid & 1, lq = lane >> 4, lr = lane & 15;
  __shared__ short As[2][64][LK];
  __shared__ short Bs[2][128][LK];
  f32x4 acc[2][4];
#pragma unroll
  for (int m = 0; m < 2; ++m)
#pragma unroll
    for (int n = 0; n < 4; ++n) acc[m][n] = (f32x4){0.f, 0.f, 0.f, 0.f};
  int lrow = lane >> 3;
  int sw = ((lane & 7) ^ lrow) * 8;  // inverse read-swizzle on source
  const short* apg[2];
  const short* bpg[4];
#pragma unroll
  for (int j = 0; j < 2; ++j)
    apg[j] = Xb + (size_t)(i0 + wid * 16 + j * 8 + lrow) * ld + sw;
#pragma unroll
  for (int j = 0; j < 4; ++j)
    bpg[j] = Xb + (size_t)(j0 + wid * 32 + j * 8 + lrow) * ld + sw;

  auto stage = [&](int p, int k0) {
    int seg = SPLIT ? (k0 / 768) : 0;
    int kl = k0 - seg * 768;
    int ak = kl + ((SPLIT && seg == 1) ? 768 : 0);
    int bk = kl + ((SPLIT && seg == 2) ? 768 : 0);
#pragma unroll
    for (int j = 0; j < 2; ++j) gl16(apg[j] + ak, &As[p][wid * 16 + j * 8][0]);
#pragma unroll
    for (int j = 0; j < 4; ++j) gl16(bpg[j] + bk, &Bs[p][wid * 32 + j * 8][0]);
  };

  const int NK = (SPLIT ? 2304 : D_) / LK;
  stage(0, 0);
  __syncthreads();
  for (int k = 0; k < NK; ++k) {
    if (k + 1 < NK) stage((k + 1) & 1, (k + 1) * LK);
    mfma2(As[k & 1], Bs[k & 1], acc, wr, wc, lq, lr);
    __syncthreads();
  }
  float* Cb = Sout + (size_t)b * L_ * L_;
#pragma unroll
  for (int m = 0; m < 2; ++m)
#pragma unroll
    for (int n = 0; n < 4; ++n)
#pragma unroll
      for (int rr = 0; rr < 4; ++rr)
        Cb[(size_t)(i0 + wr * 32 + m * 16 + 4 * lq + rr) * L_ +
           (j0 + wc * 64 + n * 16 + lr)] = acc[m][n][rr];
}

// ---------------------------------------------------------------------------
// conv1d(k=3,pad1) im2col GEMM + bias + relu + rowsumsq. 128x128 tile, dbuf.
// OOB halo rows read from zeroed scratch via per-lane pointer redirect.
// ---------------------------------------------------------------------------
template <int WF32>
__global__ __launch_bounds__(256) void k_conv_mfma(const short* __restrict__ X, int ldx,
                                                   const short* __restrict__ Wt2,
                                                   const float* __restrict__ bias,
                                                   short* __restrict__ Ybf,
                                                   float* __restrict__ Yf,
                                                   float* __restrict__ rnsq,
                                                   const short* __restrict__ zbuf) {
  int wg = xcd_remap(blockIdx.x, gridDim.x);
  int ob = wg % 6;
  int m_ = wg / 6;
  int b = m_ >> 2, l0 = (m_ & 3) * 128, o0 = ob * 128;
  const short* Xb = X + (size_t)b * L_ * ldx;
  int t = threadIdx.x, lane = t & 63, wid = t >> 6;
  int wr = wid >> 1, wc = wid & 1, lq = lane >> 4, lr = lane & 15;
  __shared__ short As[2][128][LK];
  __shared__ short Bs[2][128][LK];
  f32x4 acc[4][4];
#pragma unroll
  for (int m = 0; m < 4; ++m)
#pragma unroll
    for (int n = 0; n < 4; ++n) acc[m][n] = (f32x4){0.f, 0.f, 0.f, 0.f};
  int lrow = lane >> 3;
  int sw = ((lane & 7) ^ lrow) * 8;
  int arow[4];
  const short* bpg[4];
#pragma unroll
  for (int j = 0; j < 4; ++j) {
    arow[j] = l0 + wid * 32 + j * 8 + lrow;
    bpg[j] = Wt2 + (size_t)(o0 + wid * 32 + j * 8 + lrow) * (3 * D_) + sw;
  }
  const short* zp = zbuf + sw;

  auto stage = [&](int p, int k0) {
    int tap = k0 / D_;
    int kl = k0 - tap * D_;
#pragma unroll
    for (int j = 0; j < 4; ++j) {
      int l = arow[j] + tap - 1;
      const short* src =
          ((unsigned)l < (unsigned)L_) ? Xb + (size_t)l * ldx + kl + sw : zp;
      gl16(src, &As[p][wid * 32 + j * 8][0]);
    }
#pragma unroll
    for (int j = 0; j < 4; ++j) gl16(bpg[j] + k0, &Bs[p][wid * 32 + j * 8][0]);
  };

  const int NK = 3 * D_ / LK;  // 36
  stage(0, 0);
  __syncthreads();
  for (int k = 0; k < NK; ++k) {
    if (k + 1 < NK) stage((k + 1) & 1, (k + 1) * LK);
    mfma4(As[k & 1], Bs[k & 1], acc, wr, wc, lq, lr);
    __syncthreads();
  }
  float bv[4];
#pragma unroll
  for (int n = 0; n < 4; ++n) bv[n] = bias[o0 + wc * 64 + n * 16 + lr];
#pragma unroll
  for (int m = 0; m < 4; ++m)
#pragma unroll
    for (int rr = 0; rr < 4; ++rr) {
      int l = l0 + wr * 64 + m * 16 + 4 * lq + rr;
      size_t rowoff = ((size_t)b * L_ + l) * D_;
      float ss = 0.f;
#pragma unroll
      for (int n = 0; n < 4; ++n) {
        int o = o0 + wc * 64 + n * 16 + lr;
        float v = fmaxf(acc[m][n][rr] + bv[n], 0.f);
        Ybf[rowoff + o] = f2bf(v);
        if (WF32) Yf[rowoff + o] = v;
        ss += v * v;
      }
      ss += __shfl_xor(ss, 1);
      ss += __shfl_xor(ss, 2);
      ss += __shfl_xor(ss, 4);
      ss += __shfl_xor(ss, 8);
      if (lr == 0) atomicAdd(&rnsq[(size_t)b * L_ + l], ss);
    }
}

// ---------------------------------------------------------------------------
// att apply: R[b][i][hop][:] = P[b][i][:]*V; P bf16 [L][L], Vt bf16 [D][L].
// 128x128 tile, dbuf.
// ---------------------------------------------------------------------------
__global__ __launch_bounds__(256) void k_att_mfma(const short* __restrict__ P,
                                                  const short* __restrict__ Vt,
                                                  short* __restrict__ Rb, int hop) {
  int wg = xcd_remap(blockIdx.x, gridDim.x);
  int db = wg % 6;
  int r2 = wg / 6;
  int b = r2 >> 2, i0 = (r2 & 3) * 128, d0 = db * 128;
  const short* Pb = P + (size_t)b * L_ * L_;
  const short* Vb = Vt + (size_t)b * D_ * L_;
  int t = threadIdx.x, lane = t & 63, wid = t >> 6;
  int wr = wid >> 1, wc = wid & 1, lq = lane >> 4, lr = lane & 15;
  __shared__ short As[2][128][LK];
  __shared__ short Bs[2][128][LK];
  f32x4 acc[4][4];
#pragma unroll
  for (int m = 0; m < 4; ++m)
#pragma unroll
    for (int n = 0; n < 4; ++n) acc[m][n] = (f32x4){0.f, 0.f, 0.f, 0.f};
  int lrow = lane >> 3;
  int sw = ((lane & 7) ^ lrow) * 8;
  const short* apg[4];
  const short* bpg[4];
#pragma unroll
  for (int j = 0; j < 4; ++j) {
    apg[j] = Pb + (size_t)(i0 + wid * 32 + j * 8 + lrow) * L_ + sw;
    bpg[j] = Vb + (size_t)(d0 + wid * 32 + j * 8 + lrow) * L_ + sw;
  }
  auto stage = [&](int p, int k0) {
#pragma unroll
    for (int j = 0; j < 4; ++j) gl16(apg[j] + k0, &As[p][wid * 32 + j * 8][0]);
#pragma unroll
    for (int j = 0; j < 4; ++j) gl16(bpg[j] + k0, &Bs[p][wid * 32 + j * 8][0]);
  };

  const int NK = L_ / LK;  // 8
  stage(0, 0);
  __syncthreads();
  for (int k = 0; k < NK; ++k) {
    if (k + 1 < NK) stage((k + 1) & 1, (k + 1) * LK);
    mfma4(As[k & 1], Bs[k & 1], acc, wr, wc, lq, lr);
    __syncthreads();
  }
#pragma unroll
  for (int m = 0; m < 4; ++m)
#pragma unroll
    for (int n = 0; n < 4; ++n)
#pragma unroll
      for (int rr = 0; rr < 4; ++rr) {
        int i = i0 + wr * 64 + m * 16 + 4 * lq + rr;
        int d = d0 + wc * 64 + n * 16 + lr;
        Rb[((size_t)(b * L_ + i) * 4 + hop) * D_ + d] = f2bf(acc[m][n][rr]);
      }
}

// ---------------------------------------------------------------------------
// pool GEMM + fast-tanh·w2 epilogue. 128x128 tile, dbuf. Rb [32768][768] bf16.
// ---------------------------------------------------------------------------
__global__ __launch_bounds__(256) void k_pool_mfma(const short* __restrict__ Rb,
                                                   const short* __restrict__ W1t,
                                                   const float* __restrict__ b1,
                                                   const float* __restrict__ w2,
                                                   float* __restrict__ ps) {
  int wg = xcd_remap(blockIdx.x, gridDim.x);
  int eb = wg % 6;
  int r0 = (wg / 6) * 128, e0 = eb * 128;
  int t = threadIdx.x, lane = t & 63, wid = t >> 6;
  int wr = wid >> 1, wc = wid & 1, lq = lane >> 4, lr = lane & 15;
  __shared__ short As[2][128][LK];
  __shared__ short Bs[2][128][LK];
  f32x4 acc[4][4];
#pragma unroll
  for (int m = 0; m < 4; ++m)
#pragma unroll
    for (int n = 0; n < 4; ++n) acc[m][n] = (f32x4){0.f, 0.f, 0.f, 0.f};
  int lrow = lane >> 3;
  int sw = ((lane & 7) ^ lrow) * 8;
  const short* apg[4];
  const short* bpg[4];
#pragma unroll
  for (int j = 0; j < 4; ++j) {
    apg[j] = Rb + (size_t)(r0 + wid * 32 + j * 8 + lrow) * D_ + sw;
    bpg[j] = W1t + (size_t)(e0 + wid * 32 + j * 8 + lrow) * D_ + sw;
  }
  auto stage = [&](int p, int k0) {
#pragma unroll
    for (int j = 0; j < 4; ++j) gl16(apg[j] + k0, &As[p][wid * 32 + j * 8][0]);
#pragma unroll
    for (int j = 0; j < 4; ++j) gl16(bpg[j] + k0, &Bs[p][wid * 32 + j * 8][0]);
  };

  const int NK = D_ / LK;  // 12
  stage(0, 0);
  __syncthreads();
  for (int k = 0; k < NK; ++k) {
    if (k + 1 < NK) stage((k + 1) & 1, (k + 1) * LK);
    mfma4(As[k & 1], Bs[k & 1], acc, wr, wc, lq, lr);
    __syncthreads();
  }
  float b1v[4], w2v[4];
#pragma unroll
  for (int n = 0; n < 4; ++n) {
    int e = e0 + wc * 64 + n * 16 + lr;
    b1v[n] = b1[e];
    w2v[n] = w2[e];
  }
#pragma unroll
  for (int m = 0; m < 4; ++m)
#pragma unroll
    for (int rr = 0; rr < 4; ++rr) {
      float p = 0.f;
#pragma unroll
      for (int n = 0; n < 4; ++n) p += tanh_fast(acc[m][n][rr] + b1v[n]) * w2v[n];
      p += __shfl_xor(p, 1);
      p += __shfl_xor(p, 2);
      p += __shfl_xor(p, 4);
      p += __shfl_xor(p, 8);
      if (lr == 0) atomicAdd(&ps[r0 + wr * 64 + m * 16 + 4 * lq + rr], p);
    }
}

// ---------------------------------------------------------------------------
// bf16 transpose: in [L][ld] -> outT [D][L] (per batch)
// ---------------------------------------------------------------------------
__global__ __launch_bounds__(256) void k_transp(const short* __restrict__ in, int ld,
                                                short* __restrict__ outT) {
  int l0 = blockIdx.x * 32, d0 = blockIdx.y * 32, b = blockIdx.z;
  __shared__ short tile[32][34];
  int r = threadIdx.x >> 5, c = threadIdx.x & 31;
  const short* ib = in + (size_t)b * L_ * ld;
#pragma unroll
  for (int i = 0; i < 4; ++i)
    tile[r + 8 * i][c] = ib[(size_t)(l0 + r + 8 * i) * ld + d0 + c];
  __syncthreads();
  short* ob = outT + (size_t)b * D_ * L_;
#pragma unroll
  for (int i = 0; i < 4; ++i)
    ob[(size_t)(d0 + r + 8 * i) * L_ + l0 + c] = tile[c][r + 8 * i];
}

// ---------------------------------------------------------------------------
// softmask: one wave per row. S f32 -> P bf16.
// ---------------------------------------------------------------------------
template <int NORM>
__global__ __launch_bounds__(256) void k_softmask3(const float* __restrict__ S,
                                                   const float* __restrict__ mask,
                                                   const float* __restrict__ rsq,
                                                   short* __restrict__ P) {
  int b = blockIdx.y;
  int i = blockIdx.x * 4 + (threadIdx.x >> 6);
  int l = threadIdx.x & 63;
  const float* row = S + ((size_t)b * L_ + i) * L_;
  const float* mb = mask + (size_t)b * L_;
  float v[8], mk[8];
  {
    float4 s0 = ((const float4*)row)[l * 2];
    float4 s1 = ((const float4*)row)[l * 2 + 1];
    float4 m0 = ((const float4*)mb)[l * 2];
    float4 m1 = ((const float4*)mb)[l * 2 + 1];
    v[0] = s0.x; v[1] = s0.y; v[2] = s0.z; v[3] = s0.w;
    v[4] = s1.x; v[5] = s1.y; v[6] = s1.z; v[7] = s1.w;
    mk[0] = m0.x; mk[1] = m0.y; mk[2] = m0.z; mk[3] = m0.w;
    mk[4] = m1.x; mk[5] = m1.y; mk[6] = m1.z; mk[7] = m1.w;
  }
  if (NORM) {
    float ri = 1.f / fmaxf(sqrtf(rsq[(size_t)b * L_ + i]), 1e-12f);
    const float4* rq = (const float4*)(rsq + (size_t)b * L_);
    float4 q0 = rq[l * 2], q1 = rq[l * 2 + 1];
    float qq[8] = {q0.x, q0.y, q0.z, q0.w, q1.x, q1.y, q1.z, q1.w};
#pragma unroll
    for (int e = 0; e < 8; ++e) v[e] *= ri / fmaxf(sqrtf(qq[e]), 1e-12f);
  }
  float m = v[0];
#pragma unroll
  for (int e = 1; e < 8; ++e) m = fmaxf(m, v[e]);
#pragma unroll
  for (int s = 1; s < 64; s <<= 1) m = fmaxf(m, __shfl_xor(m, s));
  float y[8], sum = 0.f;
#pragma unroll
  for (int e = 0; e < 8; ++e) {
    y[e] = __expf(v[e] - m) * mk[e];
    sum += y[e];
  }
#pragma unroll
  for (int s = 1; s < 64; s <<= 1) sum += __shfl_xor(sum, s);
  float inv = mb[i] / (sum + 1e-10f);
  s16x8 pk;
#pragma unroll
  for (int e = 0; e < 8; ++e) pk[e] = f2bf(y[e] * inv);
  ((s16x8*)(P + ((size_t)b * L_ + i) * L_))[l] = pk;
}

// inputs f32 -> Xs bf16 [B*L][1536] = [hi | lo]
__global__ void k_prep4(const float* __restrict__ in, short* __restrict__ Xs) {
  size_t idx = (size_t)blockIdx.x * 256 + threadIdx.x;
  if (idx >= (size_t)B_ * L_ * D_ / 4) return;
  float4 x = ((const float4*)in)[idx];
  size_t base = idx * 4;
  size_t bl = base / D_;
  int d = (int)(base % D_);
  float xs[4] = {x.x, x.y, x.z, x.w};
  s16x4 hi, lo;
#pragma unroll
  for (int e = 0; e < 4; ++e) {
    hi[e] = f2bf(xs[e]);
    lo[e] = f2bf(xs[e] - bf2f(hi[e]));
  }
  *(s16x4*)&Xs[bl * 1536 + d] = hi;
  *(s16x4*)&Xs[bl * 1536 + 768 + d] = lo;
}

// conv_w [h][o][i][kk] -> Wt2 bf16 [h][o][kk*768+i]
__global__ void k_wtrans2(const float* __restrict__ w, short* __restrict__ Wt2) {
  size_t idx = (size_t)blockIdx.x * 256 + threadIdx.x;
  const size_t total = (size_t)HOPS_ * D_ * 3 * D_;
  if (idx >= total) return;
  int i = (int)(idx % D_);
  size_t tmp = idx / D_;
  int kk = (int)(tmp % 3);
  tmp /= 3;
  int o = (int)(tmp % D_);
  int h = (int)(tmp / D_);
  Wt2[idx] = f2bf(w[(((size_t)h * D_ + o) * D_ + i) * 3 + kk]);
}

// W1 [d][e] -> W1t bf16 [e][d]
__global__ void k_w1t(const float* __restrict__ W1, short* __restrict__ W1t) {
  size_t idx = (size_t)blockIdx.x * 256 + threadIdx.x;
  if (idx >= (size_t)D_ * D_) return;
  int e = (int)(idx / D_), d = (int)(idx % D_);
  W1t[idx] = f2bf(W1[(size_t)d * D_ + e]);
}

// out[b][l][d] = sum_h softmax(ps)[h] * Rb[bl][h][d]
__global__ __launch_bounds__(256) void k_weighted2(const short* __restrict__ Rb,
                                                   const float* __restrict__ ps,
                                                   float* __restrict__ out) {
  int b = blockIdx.y, l = blockIdx.x;
  size_t bl = (size_t)b * L_ + l;
  const float* p = ps + bl * 4;
  float s0 = p[0], s1 = p[1], s2 = p[2], s3 = p[3];
  float m = fmaxf(fmaxf(s0, s1), fmaxf(s2, s3));
  float e0 = __expf(s0 - m), e1 = __expf(s1 - m), e2 = __expf(s2 - m),
        e3 = __expf(s3 - m);
  float inv = 1.f / (e0 + e1 + e2 + e3);
  e0 *= inv; e1 *= inv; e2 *= inv; e3 *= inv;
  const short* Rrow = Rb + bl * 4 * D_;
  float* orow = out + bl * D_;
  for (int d = threadIdx.x; d < D_; d += 256) {
    orow[d] = e0 * bf2f(Rrow[d]) + e1 * bf2f(Rrow[D_ + d]) +
              e2 * bf2f(Rrow[2 * D_ + d]) + e3 * bf2f(Rrow[3 * D_ + d]);
  }
}

extern "C" void kernel_launch(void* const* d_in, const int* in_sizes, int n_in,
                              void* d_out, int out_size, void* d_ws, size_t ws_size,
                              hipStream_t stream) {
  const float* inputs  = (const float*)d_in[0];
  const float* mask    = (const float*)d_in[1];
  const float* conv_w  = (const float*)d_in[2];
  const float* conv_b  = (const float*)d_in[3];
  const float* pool_w1 = (const float*)d_in[4];
  const float* pool_b1 = (const float*)d_in[5];
  const float* pool_w2 = (const float*)d_in[6];
  float* out = (float*)d_out;

  const size_t BLD = (size_t)B_ * L_ * D_;
  const size_t BLL = (size_t)B_ * L_ * L_;

  char* w = (char*)d_ws;
  short* Xs   = (short*)w; w += (size_t)2 * BLD * 2;               // 25.2 MB [hi|lo]
  short* Wt2  = (short*)w; w += (size_t)HOPS_ * 3 * D_ * D_ * 2;   // 10.6 MB
  short* W1t  = (short*)w; w += (size_t)D_ * D_ * 2;               // 1.2 MB
  float* S    = (float*)w; w += BLL * 4;                           // 16.8 MB
  short* Pb   = (short*)w; w += BLL * 2;                           // 8.4 MB
  short* YbfA = (short*)w; w += BLD * 2;                           // 12.6 MB
  short* YbfB = (short*)w; w += BLD * 2;                           // 12.6 MB
  short* Vt   = (short*)w; w += BLD * 2;                           // 12.6 MB
  short* Rb   = (short*)w; w += 4 * BLD * 2;                       // 50.3 MB
  float* rnsq = (float*)w; w += (size_t)B_ * L_ * 4;
  float* ps   = (float*)w; w += (size_t)B_ * L_ * 4 * 4;
  short* zbuf = (short*)w; w += 1024;                              // zero halo page

  // --- prep ---
  hipMemsetAsync(zbuf, 0, 1024, stream);
  k_prep4<<<dim3((unsigned)((BLD / 4 + 255) / 256)), 256, 0, stream>>>(inputs, Xs);
  {
    size_t tot = (size_t)HOPS_ * D_ * 3 * D_;
    k_wtrans2<<<dim3((unsigned)((tot + 255) / 256)), 256, 0, stream>>>(conv_w, Wt2);
  }
  k_w1t<<<dim3((unsigned)(((size_t)D_ * D_ + 255) / 256)), 256, 0, stream>>>(pool_w1, W1t);

  dim3 gtr(L_ / 32, D_ / 32, B_);
  dim3 gsm(L_ / 4, B_);
  dim3 grow(L_, B_);
  const int GSIM = (L_ / 64) * (L_ / 128) * B_;        // 512
  const int GCONV = (D_ / 128) * (L_ / 128) * B_;      // 384
  const int GATT = GCONV;                              // 384
  const int GPOOL = (D_ / 128) * (4 * B_ * L_ / 128);  // 1536

  // --- hop 0: split-bf16 similarity on raw inputs ---
  k_transp<<<gtr, 256, 0, stream>>>(Xs, 1536, Vt);
  k_sim_mfma<1><<<GSIM, 256, 0, stream>>>(Xs, S);
  k_softmask3<0><<<gsm, 256, 0, stream>>>(S, mask, nullptr, Pb);
  k_att_mfma<<<GATT, 256, 0, stream>>>(Pb, Vt, Rb, 0);

  // --- hops 1..3 ---
  const short* cur = Xs;
  int ldc = 1536;
  for (int h = 0; h < HOPS_; ++h) {
    short* cv = (h & 1) ? YbfB : YbfA;
    const short* Wh = Wt2 + (size_t)h * 3 * D_ * D_;
    const float* bh = conv_b + (size_t)h * D_;
    hipMemsetAsync(rnsq, 0, (size_t)B_ * L_ * sizeof(float), stream);
    if (h == HOPS_ - 1)
      k_conv_mfma<1><<<GCONV, 256, 0, stream>>>(cur, ldc, Wh, bh, cv, out, rnsq, zbuf);
    else
      k_conv_mfma<0><<<GCONV, 256, 0, stream>>>(cur, ldc, Wh, bh, cv, nullptr, rnsq, zbuf);
    k_transp<<<gtr, 256, 0, stream>>>(cv, D_, Vt);
    k_sim_mfma<0><<<GSIM, 256, 0, stream>>>(cv, S);
    k_softmask3<1><<<gsm, 256, 0, stream>>>(S, mask, rnsq, Pb);
    k_att_mfma<<<GATT, 256, 0, stream>>>(Pb, Vt, Rb, h + 1);
    cur = cv;
    ldc = D_;
  }

  // --- pooling ---
  hipMemsetAsync(ps, 0, (size_t)B_ * L_ * 4 * sizeof(float), stream);
  k_pool_mfma<<<GPOOL, 256, 0, stream>>>(Rb, W1t, pool_b1, pool_w2, ps);
  k_weighted2<<<grow, 256, 0, stream>>>(Rb, ps, out + BLD);
}

// Round 7
// 483.018 us; speedup vs baseline: 1.0929x; 1.0929x over previous
//
#include <hip/hip_runtime.h>
#include <math.h>

#define B_ 16
#define L_ 512
#define D_ 768
#define HOPS_ 3
#define LK 64  // shorts per LDS row = 128B = 8 16B slots

typedef __attribute__((ext_vector_type(8))) short s16x8;
typedef __attribute__((ext_vector_type(4))) short s16x4;
typedef __attribute__((ext_vector_type(4))) float f32x4;

typedef __attribute__((address_space(1))) const unsigned gu32;
typedef __attribute__((address_space(3))) unsigned lu32;

// async global->LDS, 16B/lane. LDS dest: wave-uniform base + lane*16 (linear).
__device__ __forceinline__ void gl16(const void* g, void* l) {
  __builtin_amdgcn_global_load_lds((gu32*)g, (lu32*)l, 16, 0, 0);
}

__device__ __forceinline__ short f2bf(float f) {
  unsigned u = __float_as_uint(f);
  unsigned r = (u + 0x7fffu + ((u >> 16) & 1u)) >> 16;
  return (short)r;
}
__device__ __forceinline__ float bf2f(short s) {
  unsigned u = ((unsigned)(unsigned short)s) << 16;
  return __uint_as_float(u);
}
__device__ __forceinline__ float tanh_fast(float x) {
  float e = __expf(2.f * x);  // inf-safe: +inf -> 1, 0 -> -1
  return 1.f - 2.f / (e + 1.f);
}

// READ-side swizzle: phys slot = slot ^ (row&7). LDS written linearly by
// global_load_lds; inverse permutation applied to the per-lane GLOBAL source
// address (sw term). Verified r3-r6: SQ_LDS_BANK_CONFLICT == 0.
__device__ __forceinline__ s16x8* lds_slot(short (*T)[LK], int row, int slot) {
  return (s16x8*)&T[row][(slot ^ (row & 7)) * 8];
}

// 128x128 tile, 4 waves (2x2 of 64x64), K-step 64
__device__ __forceinline__ void mfma4(short (*As)[LK], short (*Bs)[LK],
                                      f32x4 acc[4][4], int wr, int wc, int lq, int lr) {
#pragma unroll
  for (int ks = 0; ks < 2; ++ks) {
    int sl = ks * 4 + lq;
    s16x8 av[4], bv[4];
#pragma unroll
    for (int m = 0; m < 4; ++m) av[m] = *lds_slot(As, wr * 64 + m * 16 + lr, sl);
#pragma unroll
    for (int n = 0; n < 4; ++n) bv[n] = *lds_slot(Bs, wc * 64 + n * 16 + lr, sl);
#pragma unroll
    for (int m = 0; m < 4; ++m)
#pragma unroll
      for (int n = 0; n < 4; ++n)
        acc[m][n] = __builtin_amdgcn_mfma_f32_16x16x32_bf16(av[m], bv[n], acc[m][n], 0, 0, 0);
  }
}

// 64x128 tile, 4 waves (2x2 of 32x64), K-step 64
__device__ __forceinline__ void mfma2(short (*As)[LK], short (*Bs)[LK],
                                      f32x4 acc[2][4], int wr, int wc, int lq, int lr) {
#pragma unroll
  for (int ks = 0; ks < 2; ++ks) {
    int sl = ks * 4 + lq;
    s16x8 av[2], bv[4];
#pragma unroll
    for (int m = 0; m < 2; ++m) av[m] = *lds_slot(As, wr * 32 + m * 16 + lr, sl);
#pragma unroll
    for (int n = 0; n < 4; ++n) bv[n] = *lds_slot(Bs, wc * 64 + n * 16 + lr, sl);
#pragma unroll
    for (int m = 0; m < 2; ++m)
#pragma unroll
      for (int n = 0; n < 4; ++n)
        acc[m][n] = __builtin_amdgcn_mfma_f32_16x16x32_bf16(av[m], bv[n], acc[m][n], 0, 0, 0);
  }
}

__device__ __forceinline__ int xcd_remap(int bid, int n) {
  return (bid & 7) * (n >> 3) + (bid >> 3);
}

// ---------------------------------------------------------------------------
// sim: S[b][i][j] = sum_k A[i][k]*A[j][k].  SPLIT=1: Xs [L][1536] hi|lo,
// virtual K=2304: A segs {hi,lo,hi}, B segs {hi,hi,lo}. 64x128 tile.
// Single-buffer 2-barrier (r5 structure — proven best; dbuf regressed r6).
// ---------------------------------------------------------------------------
template <int SPLIT>
__global__ __launch_bounds__(256) void k_sim_mfma(const short* __restrict__ X,
                                                  float* __restrict__ Sout) {
  int wg = xcd_remap(blockIdx.x, gridDim.x);
  int jb = wg & 3, ib = (wg >> 2) & 7, b = wg >> 5;
  int i0 = ib * 64, j0 = jb * 128;
  const int ld = SPLIT ? 1536 : D_;
  const short* Xb = X + (size_t)b * L_ * ld;
  int t = threadIdx.x, lane = t & 63, wid = t >> 6;
  int wr = wid >> 1, wc = wid & 1, lq = lane >> 4, lr = lane & 15;
  __shared__ short As[64][LK];
  __shared__ short Bs[128][LK];
  f32x4 acc[2][4];
#pragma unroll
  for (int m = 0; m < 2; ++m)
#pragma unroll
    for (int n = 0; n < 4; ++n) acc[m][n] = (f32x4){0.f, 0.f, 0.f, 0.f};
  int lrow = lane >> 3;
  int sw = ((lane & 7) ^ lrow) * 8;  // inverse read-swizzle on source
  const short* apg[2];
  const short* bpg[4];
#pragma unroll
  for (int j = 0; j < 2; ++j)
    apg[j] = Xb + (size_t)(i0 + wid * 16 + j * 8 + lrow) * ld + sw;
#pragma unroll
  for (int j = 0; j < 4; ++j)
    bpg[j] = Xb + (size_t)(j0 + wid * 32 + j * 8 + lrow) * ld + sw;

  const int K = SPLIT ? 2304 : D_;
  for (int k0 = 0; k0 < K; k0 += LK) {
    int seg = SPLIT ? (k0 / 768) : 0;
    int kl = k0 - seg * 768;
    int ak = kl + ((SPLIT && seg == 1) ? 768 : 0);
    int bk = kl + ((SPLIT && seg == 2) ? 768 : 0);
#pragma unroll
    for (int j = 0; j < 2; ++j) gl16(apg[j] + ak, &As[wid * 16 + j * 8][0]);
#pragma unroll
    for (int j = 0; j < 4; ++j) gl16(bpg[j] + bk, &Bs[wid * 32 + j * 8][0]);
    __syncthreads();
    mfma2(As, Bs, acc, wr, wc, lq, lr);
    __syncthreads();
  }
  float* Cb = Sout + (size_t)b * L_ * L_;
#pragma unroll
  for (int m = 0; m < 2; ++m)
#pragma unroll
    for (int n = 0; n < 4; ++n)
#pragma unroll
      for (int rr = 0; rr < 4; ++rr)
        Cb[(size_t)(i0 + wr * 32 + m * 16 + 4 * lq + rr) * L_ +
           (j0 + wc * 64 + n * 16 + lr)] = acc[m][n][rr];
}

// ---------------------------------------------------------------------------
// conv1d(k=3,pad1) im2col GEMM + bias + relu + rowsumsq + fused V^T write.
// 128x128 tile, single-buffer. Epilogue: acc -> LDS (transposed, padded rows)
// -> coalesced Vt[b][o][l] stores. Deletes the standalone transpose kernel.
// ---------------------------------------------------------------------------
template <int WF32>
__global__ __launch_bounds__(256) void k_conv_mfma(const short* __restrict__ X, int ldx,
                                                   const short* __restrict__ Wt2,
                                                   const float* __restrict__ bias,
                                                   short* __restrict__ Ybf,
                                                   float* __restrict__ Yf,
                                                   float* __restrict__ rnsq,
                                                   const short* __restrict__ zbuf,
                                                   short* __restrict__ Vt) {
  int wg = xcd_remap(blockIdx.x, gridDim.x);
  int ob = wg % 6;
  int m_ = wg / 6;
  int b = m_ >> 2, l0 = (m_ & 3) * 128, o0 = ob * 128;
  const short* Xb = X + (size_t)b * L_ * ldx;
  int t = threadIdx.x, lane = t & 63, wid = t >> 6;
  int wr = wid >> 1, wc = wid & 1, lq = lane >> 4, lr = lane & 15;
  __shared__ short smem[17408];  // GEMM: As[128][64]+Bs[128][64]=32KB; T[128][136]=34.8KB
  short (*As)[LK] = (short(*)[LK])smem;
  short (*Bs)[LK] = (short(*)[LK])(smem + 128 * LK);
  f32x4 acc[4][4];
#pragma unroll
  for (int m = 0; m < 4; ++m)
#pragma unroll
    for (int n = 0; n < 4; ++n) acc[m][n] = (f32x4){0.f, 0.f, 0.f, 0.f};
  int lrow = lane >> 3;
  int sw = ((lane & 7) ^ lrow) * 8;
  int arow[4];
  const short* bpg[4];
#pragma unroll
  for (int j = 0; j < 4; ++j) {
    arow[j] = l0 + wid * 32 + j * 8 + lrow;
    bpg[j] = Wt2 + (size_t)(o0 + wid * 32 + j * 8 + lrow) * (3 * D_) + sw;
  }
  const short* zp = zbuf + sw;

  for (int k0 = 0; k0 < 3 * D_; k0 += LK) {
    int tap = k0 / D_;
    int kl = k0 - tap * D_;
#pragma unroll
    for (int j = 0; j < 4; ++j) {
      int l = arow[j] + tap - 1;
      const short* src =
          ((unsigned)l < (unsigned)L_) ? Xb + (size_t)l * ldx + kl + sw : zp;
      gl16(src, &As[wid * 32 + j * 8][0]);
    }
#pragma unroll
    for (int j = 0; j < 4; ++j) gl16(bpg[j] + k0, &Bs[wid * 32 + j * 8][0]);
    __syncthreads();
    mfma4(As, Bs, acc, wr, wc, lq, lr);
    __syncthreads();
  }
  float bv[4];
#pragma unroll
  for (int n = 0; n < 4; ++n) bv[n] = bias[o0 + wc * 64 + n * 16 + lr];
  // relu in place
#pragma unroll
  for (int m = 0; m < 4; ++m)
#pragma unroll
    for (int n = 0; n < 4; ++n)
#pragma unroll
      for (int rr = 0; rr < 4; ++rr)
        acc[m][n][rr] = fmaxf(acc[m][n][rr] + bv[n], 0.f);
  // row-major Ybf (+Yf) + rowsumsq
#pragma unroll
  for (int m = 0; m < 4; ++m)
#pragma unroll
    for (int rr = 0; rr < 4; ++rr) {
      int l = l0 + wr * 64 + m * 16 + 4 * lq + rr;
      size_t rowoff = ((size_t)b * L_ + l) * D_;
      float ss = 0.f;
#pragma unroll
      for (int n = 0; n < 4; ++n) {
        int o = o0 + wc * 64 + n * 16 + lr;
        float v = acc[m][n][rr];
        Ybf[rowoff + o] = f2bf(v);
        if (WF32) Yf[rowoff + o] = v;
        ss += v * v;
      }
      ss += __shfl_xor(ss, 1);
      ss += __shfl_xor(ss, 2);
      ss += __shfl_xor(ss, 4);
      ss += __shfl_xor(ss, 8);
      if (lr == 0) atomicAdd(&rnsq[(size_t)b * L_ + l], ss);
    }
  // transposed bounce: T[o'][l'] then coalesced Vt[b][o][l]
  short (*T)[136] = (short(*)[136])smem;
#pragma unroll
  for (int m = 0; m < 4; ++m)
#pragma unroll
    for (int n = 0; n < 4; ++n) {
      int o_ = wc * 64 + n * 16 + lr;
      int lb = wr * 64 + m * 16 + 4 * lq;
      s16x4 pk;
#pragma unroll
      for (int rr = 0; rr < 4; ++rr) pk[rr] = f2bf(acc[m][n][rr]);
      *(s16x4*)&T[o_][lb] = pk;
    }
  __syncthreads();
  short* Vtb = Vt + (size_t)b * D_ * L_;
#pragma unroll
  for (int p = 0; p < 8; ++p) {
    int dl = p * 16 + (t >> 4), lc = (t & 15) * 8;
    s16x8 q = *(const s16x8*)&T[dl][lc];
    *(s16x8*)&Vtb[(size_t)(o0 + dl) * L_ + l0 + lc] = q;
  }
}

// ---------------------------------------------------------------------------
// att apply: R[b][i][hop][:] = P[b][i][:]*V; P bf16 [L][L], Vt bf16 [D][L].
// 128x128 tile, single-buffer.
// ---------------------------------------------------------------------------
__global__ __launch_bounds__(256) void k_att_mfma(const short* __restrict__ P,
                                                  const short* __restrict__ Vt,
                                                  short* __restrict__ Rb, int hop) {
  int wg = xcd_remap(blockIdx.x, gridDim.x);
  int db = wg % 6;
  int r2 = wg / 6;
  int b = r2 >> 2, i0 = (r2 & 3) * 128, d0 = db * 128;
  const short* Pb = P + (size_t)b * L_ * L_;
  const short* Vb = Vt + (size_t)b * D_ * L_;
  int t = threadIdx.x, lane = t & 63, wid = t >> 6;
  int wr = wid >> 1, wc = wid & 1, lq = lane >> 4, lr = lane & 15;
  __shared__ short As[128][LK];
  __shared__ short Bs[128][LK];
  f32x4 acc[4][4];
#pragma unroll
  for (int m = 0; m < 4; ++m)
#pragma unroll
    for (int n = 0; n < 4; ++n) acc[m][n] = (f32x4){0.f, 0.f, 0.f, 0.f};
  int lrow = lane >> 3;
  int sw = ((lane & 7) ^ lrow) * 8;
  const short* apg[4];
  const short* bpg[4];
#pragma unroll
  for (int j = 0; j < 4; ++j) {
    apg[j] = Pb + (size_t)(i0 + wid * 32 + j * 8 + lrow) * L_ + sw;
    bpg[j] = Vb + (size_t)(d0 + wid * 32 + j * 8 + lrow) * L_ + sw;
  }
  for (int k0 = 0; k0 < L_; k0 += LK) {
#pragma unroll
    for (int j = 0; j < 4; ++j) gl16(apg[j] + k0, &As[wid * 32 + j * 8][0]);
#pragma unroll
    for (int j = 0; j < 4; ++j) gl16(bpg[j] + k0, &Bs[wid * 32 + j * 8][0]);
    __syncthreads();
    mfma4(As, Bs, acc, wr, wc, lq, lr);
    __syncthreads();
  }
#pragma unroll
  for (int m = 0; m < 4; ++m)
#pragma unroll
    for (int n = 0; n < 4; ++n)
#pragma unroll
      for (int rr = 0; rr < 4; ++rr) {
        int i = i0 + wr * 64 + m * 16 + 4 * lq + rr;
        int d = d0 + wc * 64 + n * 16 + lr;
        Rb[((size_t)(b * L_ + i) * 4 + hop) * D_ + d] = f2bf(acc[m][n][rr]);
      }
}

// ---------------------------------------------------------------------------
// pool GEMM + fast-tanh·w2 epilogue. 128x128 tile, single-buffer.
// ---------------------------------------------------------------------------
__global__ __launch_bounds__(256) void k_pool_mfma(const short* __restrict__ Rb,
                                                   const short* __restrict__ W1t,
                                                   const float* __restrict__ b1,
                                                   const float* __restrict__ w2,
                                                   float* __restrict__ ps) {
  int wg = xcd_remap(blockIdx.x, gridDim.x);
  int eb = wg % 6;
  int r0 = (wg / 6) * 128, e0 = eb * 128;
  int t = threadIdx.x, lane = t & 63, wid = t >> 6;
  int wr = wid >> 1, wc = wid & 1, lq = lane >> 4, lr = lane & 15;
  __shared__ short As[128][LK];
  __shared__ short Bs[128][LK];
  f32x4 acc[4][4];
#pragma unroll
  for (int m = 0; m < 4; ++m)
#pragma unroll
    for (int n = 0; n < 4; ++n) acc[m][n] = (f32x4){0.f, 0.f, 0.f, 0.f};
  int lrow = lane >> 3;
  int sw = ((lane & 7) ^ lrow) * 8;
  const short* apg[4];
  const short* bpg[4];
#pragma unroll
  for (int j = 0; j < 4; ++j) {
    apg[j] = Rb + (size_t)(r0 + wid * 32 + j * 8 + lrow) * D_ + sw;
    bpg[j] = W1t + (size_t)(e0 + wid * 32 + j * 8 + lrow) * D_ + sw;
  }
  for (int k0 = 0; k0 < D_; k0 += LK) {
#pragma unroll
    for (int j = 0; j < 4; ++j) gl16(apg[j] + k0, &As[wid * 32 + j * 8][0]);
#pragma unroll
    for (int j = 0; j < 4; ++j) gl16(bpg[j] + k0, &Bs[wid * 32 + j * 8][0]);
    __syncthreads();
    mfma4(As, Bs, acc, wr, wc, lq, lr);
    __syncthreads();
  }
  float b1v[4], w2v[4];
#pragma unroll
  for (int n = 0; n < 4; ++n) {
    int e = e0 + wc * 64 + n * 16 + lr;
    b1v[n] = b1[e];
    w2v[n] = w2[e];
  }
#pragma unroll
  for (int m = 0; m < 4; ++m)
#pragma unroll
    for (int rr = 0; rr < 4; ++rr) {
      float p = 0.f;
#pragma unroll
      for (int n = 0; n < 4; ++n) p += tanh_fast(acc[m][n][rr] + b1v[n]) * w2v[n];
      p += __shfl_xor(p, 1);
      p += __shfl_xor(p, 2);
      p += __shfl_xor(p, 4);
      p += __shfl_xor(p, 8);
      if (lr == 0) atomicAdd(&ps[r0 + wr * 64 + m * 16 + 4 * lq + rr], p);
    }
}

// ---------------------------------------------------------------------------
// fused prep: inputs f32 -> Xs bf16 [bl][1536]=[hi|lo] AND Vt[b][d][l]=hi
// (tiled; replaces elementwise prep + hop-0 transpose)
// ---------------------------------------------------------------------------
__global__ __launch_bounds__(256) void k_prep2(const float* __restrict__ in,
                                               short* __restrict__ Xs,
                                               short* __restrict__ Vt) {
  int l0 = blockIdx.x * 32, d0 = blockIdx.y * 32, b = blockIdx.z;
  __shared__ short tile[32][40];  // [d_local][l_local], rows 80B (16B-aligned)
  int r = threadIdx.x >> 5, c = threadIdx.x & 31;
  const float* ib = in + ((size_t)b * L_ + l0) * D_ + d0;
#pragma unroll
  for (int i = 0; i < 4; ++i) {
    int rr = r + 8 * i;
    float x = ib[(size_t)rr * D_ + c];
    short hi = f2bf(x);
    short lo = f2bf(x - bf2f(hi));
    size_t bl = (size_t)b * L_ + l0 + rr;
    Xs[bl * 1536 + d0 + c] = hi;
    Xs[bl * 1536 + 768 + d0 + c] = lo;
    tile[c][rr] = hi;
  }
  __syncthreads();
  int dl = threadIdx.x >> 3, lc = (threadIdx.x & 7) * 4;
  s16x4 q = *(const s16x4*)&tile[dl][lc];
  *(s16x4*)&Vt[((size_t)b * D_ + d0 + dl) * L_ + l0 + lc] = q;
}

// ---------------------------------------------------------------------------
// merged weight prep: conv_w [h][o][i][kk] -> Wt2 bf16 [h][o][kk*768+i];
// W1 [d][e] -> W1t bf16 [e][d]
// ---------------------------------------------------------------------------
__global__ void k_wprep(const float* __restrict__ w, const float* __restrict__ W1,
                        short* __restrict__ Wt2, short* __restrict__ W1t) {
  size_t idx = (size_t)blockIdx.x * 256 + threadIdx.x;
  const size_t tot1 = (size_t)HOPS_ * D_ * 3 * D_;
  if (idx < tot1) {
    int i = (int)(idx % D_);
    size_t tmp = idx / D_;
    int kk = (int)(tmp % 3);
    tmp /= 3;
    int o = (int)(tmp % D_);
    int h = (int)(tmp / D_);
    Wt2[idx] = f2bf(w[(((size_t)h * D_ + o) * D_ + i) * 3 + kk]);
  } else {
    size_t i2 = idx - tot1;
    if (i2 >= (size_t)D_ * D_) return;
    int e = (int)(i2 / D_), d = (int)(i2 % D_);
    W1t[i2] = f2bf(W1[(size_t)d * D_ + e]);
  }
}

// ---------------------------------------------------------------------------
// softmask: one wave per row. S f32 -> P bf16.
// ---------------------------------------------------------------------------
template <int NORM>
__global__ __launch_bounds__(256) void k_softmask3(const float* __restrict__ S,
                                                   const float* __restrict__ mask,
                                                   const float* __restrict__ rsq,
                                                   short* __restrict__ P) {
  int b = blockIdx.y;
  int i = blockIdx.x * 4 + (threadIdx.x >> 6);
  int l = threadIdx.x & 63;
  const float* row = S + ((size_t)b * L_ + i) * L_;
  const float* mb = mask + (size_t)b * L_;
  float v[8], mk[8];
  {
    float4 s0 = ((const float4*)row)[l * 2];
    float4 s1 = ((const float4*)row)[l * 2 + 1];
    float4 m0 = ((const float4*)mb)[l * 2];
    float4 m1 = ((const float4*)mb)[l * 2 + 1];
    v[0] = s0.x; v[1] = s0.y; v[2] = s0.z; v[3] = s0.w;
    v[4] = s1.x; v[5] = s1.y; v[6] = s1.z; v[7] = s1.w;
    mk[0] = m0.x; mk[1] = m0.y; mk[2] = m0.z; mk[3] = m0.w;
    mk[4] = m1.x; mk[5] = m1.y; mk[6] = m1.z; mk[7] = m1.w;
  }
  if (NORM) {
    float ri = 1.f / fmaxf(sqrtf(rsq[(size_t)b * L_ + i]), 1e-12f);
    const float4* rq = (const float4*)(rsq + (size_t)b * L_);
    float4 q0 = rq[l * 2], q1 = rq[l * 2 + 1];
    float qq[8] = {q0.x, q0.y, q0.z, q0.w, q1.x, q1.y, q1.z, q1.w};
#pragma unroll
    for (int e = 0; e < 8; ++e) v[e] *= ri / fmaxf(sqrtf(qq[e]), 1e-12f);
  }
  float m = v[0];
#pragma unroll
  for (int e = 1; e < 8; ++e) m = fmaxf(m, v[e]);
#pragma unroll
  for (int s = 1; s < 64; s <<= 1) m = fmaxf(m, __shfl_xor(m, s));
  float y[8], sum = 0.f;
#pragma unroll
  for (int e = 0; e < 8; ++e) {
    y[e] = __expf(v[e] - m) * mk[e];
    sum += y[e];
  }
#pragma unroll
  for (int s = 1; s < 64; s <<= 1) sum += __shfl_xor(sum, s);
  float inv = mb[i] / (sum + 1e-10f);
  s16x8 pk;
#pragma unroll
  for (int e = 0; e < 8; ++e) pk[e] = f2bf(y[e] * inv);
  ((s16x8*)(P + ((size_t)b * L_ + i) * L_))[l] = pk;
}

// out[b][l][d] = sum_h softmax(ps)[h] * Rb[bl][h][d]
__global__ __launch_bounds__(256) void k_weighted2(const short* __restrict__ Rb,
                                                   const float* __restrict__ ps,
                                                   float* __restrict__ out) {
  int b = blockIdx.y, l = blockIdx.x;
  size_t bl = (size_t)b * L_ + l;
  const float* p = ps + bl * 4;
  float s0 = p[0], s1 = p[1], s2 = p[2], s3 = p[3];
  float m = fmaxf(fmaxf(s0, s1), fmaxf(s2, s3));
  float e0 = __expf(s0 - m), e1 = __expf(s1 - m), e2 = __expf(s2 - m),
        e3 = __expf(s3 - m);
  float inv = 1.f / (e0 + e1 + e2 + e3);
  e0 *= inv; e1 *= inv; e2 *= inv; e3 *= inv;
  const short* Rrow = Rb + bl * 4 * D_;
  float* orow = out + bl * D_;
  for (int d = threadIdx.x; d < D_; d += 256) {
    orow[d] = e0 * bf2f(Rrow[d]) + e1 * bf2f(Rrow[D_ + d]) +
              e2 * bf2f(Rrow[2 * D_ + d]) + e3 * bf2f(Rrow[3 * D_ + d]);
  }
}

extern "C" void kernel_launch(void* const* d_in, const int* in_sizes, int n_in,
                              void* d_out, int out_size, void* d_ws, size_t ws_size,
                              hipStream_t stream) {
  const float* inputs  = (const float*)d_in[0];
  const float* mask    = (const float*)d_in[1];
  const float* conv_w  = (const float*)d_in[2];
  const float* conv_b  = (const float*)d_in[3];
  const float* pool_w1 = (const float*)d_in[4];
  const float* pool_b1 = (const float*)d_in[5];
  const float* pool_w2 = (const float*)d_in[6];
  float* out = (float*)d_out;

  const size_t BLD = (size_t)B_ * L_ * D_;
  const size_t BLL = (size_t)B_ * L_ * L_;
  const size_t BL  = (size_t)B_ * L_;

  char* w = (char*)d_ws;
  short* Xs   = (short*)w; w += (size_t)2 * BLD * 2;               // 25.2 MB [hi|lo]
  short* Wt2  = (short*)w; w += (size_t)HOPS_ * 3 * D_ * D_ * 2;   // 10.6 MB
  short* W1t  = (short*)w; w += (size_t)D_ * D_ * 2;               // 1.2 MB
  float* S    = (float*)w; w += BLL * 4;                           // 16.8 MB
  short* Pb   = (short*)w; w += BLL * 2;                           // 8.4 MB
  short* YbfA = (short*)w; w += BLD * 2;                           // 12.6 MB
  short* YbfB = (short*)w; w += BLD * 2;                           // 12.6 MB
  short* Vt   = (short*)w; w += BLD * 2;                           // 12.6 MB
  short* Rb   = (short*)w; w += 4 * BLD * 2;                       // 50.3 MB
  // zero-region: [ps | rnsq x3 | zbuf] — one memset per launch
  float* ps   = (float*)w; w += BL * 4 * 4;                        // 512 KB
  float* rnsq = (float*)w; w += BL * 3 * 4;                        // 384 KB
  short* zbuf = (short*)w; w += 1024;
  const size_t zero_bytes = BL * 4 * 4 + BL * 3 * 4 + 1024;

  hipMemsetAsync(ps, 0, zero_bytes, stream);

  dim3 gpre(L_ / 32, D_ / 32, B_);  // (16,24,16)
  dim3 gsm(L_ / 4, B_);
  dim3 grow(L_, B_);
  const int GSIM = (L_ / 64) * (L_ / 128) * B_;        // 512
  const int GCONV = (D_ / 128) * (L_ / 128) * B_;      // 384
  const int GATT = GCONV;                              // 384
  const int GPOOL = (D_ / 128) * (4 * B_ * L_ / 128);  // 1536
  const size_t wtot = (size_t)HOPS_ * D_ * 3 * D_ + (size_t)D_ * D_;

  // --- prep (fused Xs + hop-0 V^T) + weights ---
  k_prep2<<<gpre, 256, 0, stream>>>(inputs, Xs, Vt);
  k_wprep<<<dim3((unsigned)((wtot + 255) / 256)), 256, 0, stream>>>(conv_w, pool_w1,
                                                                     Wt2, W1t);

  // --- hop 0: split-bf16 similarity on raw inputs ---
  k_sim_mfma<1><<<GSIM, 256, 0, stream>>>(Xs, S);
  k_softmask3<0><<<gsm, 256, 0, stream>>>(S, mask, nullptr, Pb);
  k_att_mfma<<<GATT, 256, 0, stream>>>(Pb, Vt, Rb, 0);

  // --- hops 1..3 ---
  const short* cur = Xs;
  int ldc = 1536;
  for (int h = 0; h < HOPS_; ++h) {
    short* cv = (h & 1) ? YbfB : YbfA;
    const short* Wh = Wt2 + (size_t)h * 3 * D_ * D_;
    const float* bh = conv_b + (size_t)h * D_;
    float* rq = rnsq + (size_t)h * BL;
    if (h == HOPS_ - 1)
      k_conv_mfma<1><<<GCONV, 256, 0, stream>>>(cur, ldc, Wh, bh, cv, out, rq, zbuf, Vt);
    else
      k_conv_mfma<0><<<GCONV, 256, 0, stream>>>(cur, ldc, Wh, bh, cv, nullptr, rq, zbuf, Vt);
    k_sim_mfma<0><<<GSIM, 256, 0, stream>>>(cv, S);
    k_softmask3<1><<<gsm, 256, 0, stream>>>(S, mask, rq, Pb);
    k_att_mfma<<<GATT, 256, 0, stream>>>(Pb, Vt, Rb, h + 1);
    cur = cv;
    ldc = D_;
  }

  // --- pooling ---
  k_pool_mfma<<<GPOOL, 256, 0, stream>>>(Rb, W1t, pool_b1, pool_w2, ps);
  k_weighted2<<<grow, 256, 0, stream>>>(Rb, ps, out + BLD);
}